// Round 9
// baseline (43.848 us; speedup 1.0000x reference)
//
#include <hip/hip_runtime.h>

#define NIN   784
#define NOUT  512
#define NROWS 785      // NIN + 1 (bias row)
#define NPAD  800      // 50 chunks * 16 (pad rows contribute 0)
#define BATCH 256
#define CHUNK 16       // i-rows per block
#define NZ    50

static constexpr float G_MIN_F  = (float)(1.0 / 983.3);
static constexpr float G_DIFF_F = (float)(1.0 / 281.3 - 1.0 / 983.3);

// device fast transcendental: v_log_f32 (log2), v_exp_f32 (2^x)
__device__ __forceinline__ float dlog2(float v) { return __builtin_amdgcn_logf(v); }
__device__ __forceinline__ float dexp2(float v) { return __builtin_amdgcn_exp2f(v); }

// ws layout: [0]: 128 partial maxima; [4096): LX float2[NPAD][BATCH] (1.64 MB)
#define WS_PM_OFF 0
#define WS_LX_OFF 4096
#define WS_TOTAL  (WS_LX_OFF + (size_t)NPAD * BATCH * 8)

// 256-thread-block reduce of the 128 partial maxima (all threads return max).
__device__ __forceinline__ float load_maxw(const float* __restrict__ pm, int tid) {
    float m = pm[tid & 127];
    #pragma unroll
    for (int off = 1; off < 64; off <<= 1)
        m = fmaxf(m, __shfl_xor(m, off, 64));
    __shared__ float sm2[4];
    if ((tid & 63) == 0) sm2[tid >> 6] = m;
    __syncthreads();
    return fmaxf(fmaxf(sm2[0], sm2[1]), fmaxf(sm2[2], sm2[3]));
}

// ---------------------------------------------------------------------------
// Kernel 1: per-block partial max over |weights| (vectorized) + zero d_out.
// 128 blocks x 256 threads; 32768 float4 = exactly one per thread.
// ---------------------------------------------------------------------------
__global__ __launch_bounds__(256) void mk_max(
    const float* __restrict__ wp, const float* __restrict__ wn,
    const float* __restrict__ bp, const float* __restrict__ bn,
    float* __restrict__ part, float4* __restrict__ out4)
{
    const int gid = blockIdx.x * 256 + threadIdx.x;
    out4[gid] = make_float4(0.f, 0.f, 0.f, 0.f);

    float m = 0.0f;
    const int n4 = NIN * NOUT / 4;
    const float4* wp4 = (const float4*)wp;
    const float4* wn4 = (const float4*)wn;
    for (int idx = gid; idx < n4; idx += gridDim.x * 256) {
        float4 a = wp4[idx], b = wn4[idx];
        m = fmaxf(m, fmaxf(fmaxf(fabsf(a.x), fabsf(a.y)), fmaxf(fabsf(a.z), fabsf(a.w))));
        m = fmaxf(m, fmaxf(fmaxf(fabsf(b.x), fabsf(b.y)), fmaxf(fabsf(b.z), fabsf(b.w))));
    }
    if (blockIdx.x == 0 && threadIdx.x < NOUT) {
        m = fmaxf(m, fabsf(bp[threadIdx.x]));
        m = fmaxf(m, fabsf(bn[threadIdx.x]));
    }
    #pragma unroll
    for (int off = 1; off < 64; off <<= 1)
        m = fmaxf(m, __shfl_xor(m, off, 64));
    __shared__ float sm[4];
    if ((threadIdx.x & 63) == 0) sm[threadIdx.x >> 6] = m;
    __syncthreads();
    if (threadIdx.x == 0)
        part[blockIdx.x] = fmaxf(fmaxf(sm[0], sm[1]), fmaxf(sm[2], sm[3]));
}

// ---------------------------------------------------------------------------
// Kernel 2: LX[i][bb] = {log2(2|x[bb][i]|), sign(x[bb][i])}.
// Row-transposed so mk_main's per-step 8-batch slice is 64B contiguous
// (-> one s_load_dwordx16 on the SMEM pipe). 800 blocks x 256 threads.
// Pad rows i>=NROWS get {0,0} (contribution 0). Bias row i==NIN: {1,1}.
// ---------------------------------------------------------------------------
__global__ __launch_bounds__(256) void mk_lx(
    const float* __restrict__ x, float2* __restrict__ lx)
{
    const int t  = blockIdx.x * 256 + threadIdx.x;
    const int i  = t >> 8, bb = t & 255;      // bb fastest -> coalesced writes
    float L = 0.0f, s = 0.0f;
    if (i < NIN) {
        const float v = x[bb * NIN + i];
        s = (v > 0.0f) ? 1.0f : ((v < 0.0f) ? -1.0f : 0.0f);
        L = dlog2(2.0f * fabsf(v));
    } else if (i == NIN) { L = 1.0f; s = 1.0f; }   // bias input v=1
    lx[i * BATCH + bb] = make_float2(L, s);
}

// ---------------------------------------------------------------------------
// Kernel 3: fused table+crossbar. Inner loop: 1 ds_read_b128 + scalar loads.
// y[b,j] = C * sum_i s[b,i] * ( 2^(ep*L + lgGp) - 2^(en*L + lgGn) )
// Grid (8 jtiles, 8 bgroups, 50 ichunks); 256 threads = 64 cols x 4 ty.
// LDS = 16KB table only -> 8 blocks/CU (wave-slot limit), 100% occupancy.
// {L,s} comes from ws via wave-uniform pointer (readfirstlane) -> SMEM pipe,
// keeping the per-CU LDS pipe free for the per-lane table reads.
// ---------------------------------------------------------------------------
__global__ __launch_bounds__(256) void mk_main(
    const float* __restrict__ wp, const float* __restrict__ wn,
    const float* __restrict__ bp, const float* __restrict__ bn,
    const float* __restrict__ npar, const float* __restrict__ pm,
    const float2* __restrict__ lx, float* __restrict__ out)
{
    const int tid = threadIdx.x;
    const float maxw = load_maxw(pm, tid);
    const float kG = G_DIFF_F / maxw;
    const float C  = 0.5f * maxw / G_DIFF_F;    // 0.5/kG

    const int tx = tid & 63;
    const int ty = tid >> 6;
    const int tyu = __builtin_amdgcn_readfirstlane(ty);   // provably uniform
    const int j0 = blockIdx.x * 64;
    const int jp = j0 + tx;
    const int b0 = blockIdx.y * 32;
    const int i0 = blockIdx.z * CHUNK;

    __shared__ float4 Tb[CHUNK * 64];           // {ep, lgGp, en, lgGn}

    // --- stage table slice: 1024 (ii,jj) pairs, 4 per thread, coalesced ---
    #pragma unroll
    for (int k = 0; k < 4; ++k) {
        const int p  = tid + k * 256;
        const int ii = p >> 6, jj = p & 63;
        const int i  = i0 + ii;
        float4 r = make_float4(0.f, 0.f, 0.f, 0.f);
        if (i < NROWS) {
            const float wpv = (i < NIN) ? wp[i * NOUT + j0 + jj] : bp[j0 + jj];
            const float wnv = (i < NIN) ? wn[i * NOUT + j0 + jj] : bn[j0 + jj];
            const float2 nv = *(const float2*)(&npar[i * (2 * NOUT) + 2 * (j0 + jj)]);
            r.x = dlog2(nv.x);                                  // ep
            r.y = dlog2(fmaf(kG, fmaxf(wpv, 0.0f), G_MIN_F));   // lgGp
            r.z = dlog2(nv.y);                                  // en
            r.w = dlog2(fmaf(kG, fmaxf(wnv, 0.0f), G_MIN_F));   // lgGn
        }
        Tb[p] = r;
    }
    __syncthreads();

    float acc[8];
    #pragma unroll
    for (int b = 0; b < 8; ++b) acc[b] = 0.0f;

    // wave-uniform {L,s} row pointer -> scalar (SMEM) loads
    const float2* lsrow = &lx[i0 * BATCH + b0 + tyu * 8];

    #pragma unroll
    for (int ii = 0; ii < CHUNK; ++ii) {
        const float4 tv = Tb[ii * 64 + tx];     // the ONLY LDS read per step
        float2 lsv[8];
        #pragma unroll
        for (int b = 0; b < 8; ++b)
            lsv[b] = lsrow[ii * BATCH + b];     // 64B uniform -> s_load_dwordx16
        #pragma unroll
        for (int b = 0; b < 8; ++b) {
            const float tp = dexp2(fmaf(tv.x, lsv[b].x, tv.y));
            const float tn = dexp2(fmaf(tv.z, lsv[b].x, tv.w));
            acc[b] = fmaf(lsv[b].y, tp - tn, acc[b]);
        }
    }

    #pragma unroll
    for (int b = 0; b < 8; ++b)
        unsafeAtomicAdd(&out[(b0 + ty * 8 + b) * NOUT + jp], C * acc[b]);
}

extern "C" void kernel_launch(void* const* d_in, const int* in_sizes, int n_in,
                              void* d_out, int out_size, void* d_ws, size_t ws_size,
                              hipStream_t stream) {
    const float* x    = (const float*)d_in[0];
    const float* wp   = (const float*)d_in[1];
    const float* wn   = (const float*)d_in[2];
    const float* bp   = (const float*)d_in[3];
    const float* bn   = (const float*)d_in[4];
    const float* npar = (const float*)d_in[5];
    float*        out = (float*)d_out;
    float*         pm = (float*)((char*)d_ws + WS_PM_OFF);
    float2*        lx = (float2*)((char*)d_ws + WS_LX_OFF);

    // mk_max zeroes d_out (atomic target) and writes 128 partial maxima
    mk_max<<<128, 256, 0, stream>>>(wp, wn, bp, bn, pm, (float4*)out);
    mk_lx<<<NPAD * BATCH / 256, 256, 0, stream>>>(x, lx);

    dim3 grid(NOUT / 64, BATCH / 32, NZ);
    mk_main<<<grid, 256, 0, stream>>>(wp, wn, bp, bn, npar, pm, lx, out);
}